// Round 1
// baseline (5210.129 us; speedup 1.0000x reference)
//
#include <hip/hip_runtime.h>

// ---------------------------------------------------------------------------
// 2-layer tanh SimpleRNN, BATCH=256, SEQ=80, UNITS=2048, EMBED=100 (fp32 in/out)
// Strategy: fp16 MFMA (fp32 accum) persistent kernel, 81 software-pipelined
// phases (layer0 step p || layer1 step p-1), device-wide flag barrier/phase.
// Weights pre-formatted once per call into MFMA B-fragment streams.
// ---------------------------------------------------------------------------

typedef _Float16 f16;
typedef _Float16 f16x2 __attribute__((ext_vector_type(2)));
typedef _Float16 f16x8 __attribute__((ext_vector_type(8)));
typedef float    f32x4 __attribute__((ext_vector_type(4)));

#define NWG   192
#define BATCH 256
#define SEQ   80
#define NEMB  100
#define EPAD  128
#define UNITS 2048

// ---- workspace layout (bytes) ----
#define FLAGS_OFF  0
#define HBUF_OFF   1024
#define HBUF_ONE   (BATCH * 4096 * 2)            // one h buffer: [256][4096] f16 (left=h0,right=h1)
#define B0S_OFF    (HBUF_OFF + 2 * HBUF_ONE)
#define B0S_NKC    68                            // K32 chunks for layer0 B (2048 U0 + 128 padded W0)
#define B0S_SIZE   (128 * B0S_NKC * 1024)
#define B1S_OFF    (B0S_OFF + B0S_SIZE)
#define B1S_NKC    128                           // K32 chunks for layer1 B ([W1;U1] = 4096 K)
#define B1S_SIZE   (128 * B1S_NKC * 1024)
#define XP_OFF     (B1S_OFF + B1S_SIZE)
#define XP_SIZE    (SEQ * BATCH * EPAD * 2)      // padded fp16 embedded inputs, time-major
#define WS_NEED    ((size_t)XP_OFF + XP_SIZE)    // ~35 MB

__device__ __forceinline__ float tanh_fast(float x) {
  x = fminf(15.f, fmaxf(-15.f, x));
  float e = __expf(2.f * x);
  return (e - 1.f) * __builtin_amdgcn_rcpf(e + 1.f);
}

// global->LDS direct (16B per lane; LDS dest = wave-uniform base + lane*16)
__device__ __forceinline__ void gl_lds16(const void* g, void* l) {
  __builtin_amdgcn_global_load_lds(
      (const __attribute__((address_space(1))) void*)g,
      (__attribute__((address_space(3))) void*)l, 16, 0, 0);
}

// device-wide barrier: per-WG monotone flags, agent fences (cross-XCD safe)
__device__ __forceinline__ void gbar(int* flags, int target) {
  __syncthreads();                       // all waves' stores issued+drained (vmcnt0 before s_barrier)
  if (threadIdx.x == 0) {
    __threadfence();                     // agent release: flush to coherence point
    __hip_atomic_store(&flags[blockIdx.x], target, __ATOMIC_RELAXED,
                       __HIP_MEMORY_SCOPE_AGENT);
  }
  if (threadIdx.x < NWG) {
    while (__hip_atomic_load(&flags[threadIdx.x], __ATOMIC_RELAXED,
                             __HIP_MEMORY_SCOPE_AGENT) < target)
      __builtin_amdgcn_s_sleep(2);
  }
  __syncthreads();
  __threadfence();                       // agent acquire: invalidate stale lines
}

// ---------------------------------------------------------------------------
// prologue 1: weights -> fp16 MFMA B-fragment streams
//   chunk u = [n16][k32]: 64 lanes x 8 f16, element (k=k32*32+(l>>4)*8+j, c=n16*16+(l&15))
// ---------------------------------------------------------------------------
__global__ __launch_bounds__(256) void fmt_weights(
    const float* __restrict__ W0, const float* __restrict__ U0,
    const float* __restrict__ W1, const float* __restrict__ U1,
    char* __restrict__ ws)
{
  int unit = blockIdx.x * 4 + (threadIdx.x >> 6);
  int lane = threadIdx.x & 63;
  int c_lo = lane & 15, k_lo = (lane >> 4) * 8;
  f16x8 h;
  f16* dst;
  if (unit < 128 * B0S_NKC) {
    int n16 = unit / B0S_NKC, k32 = unit % B0S_NKC;
    int c = n16 * 16 + c_lo;
#pragma unroll
    for (int j = 0; j < 8; ++j) {
      int k = k32 * 32 + k_lo + j;
      float v;
      if (k < UNITS) v = U0[(size_t)k * UNITS + c];
      else { int e = k - UNITS; v = (e < NEMB) ? W0[(size_t)e * UNITS + c] : 0.f; }
      h[j] = (f16)v;
    }
    dst = (f16*)(ws + B0S_OFF) + (size_t)unit * 512 + lane * 8;
  } else {
    int u = unit - 128 * B0S_NKC;
    int n16 = u / B1S_NKC, k32 = u % B1S_NKC;
    int c = n16 * 16 + c_lo;
#pragma unroll
    for (int j = 0; j < 8; ++j) {
      int k = k32 * 32 + k_lo + j;
      float v = (k < UNITS) ? W1[(size_t)k * UNITS + c]
                            : U1[(size_t)(k - UNITS) * UNITS + c];
      h[j] = (f16)v;
    }
    dst = (f16*)(ws + B1S_OFF) + (size_t)u * 512 + lane * 8;
  }
  *(f16x8*)dst = h;
}

// ---------------------------------------------------------------------------
// prologue 2: embedding lookup -> Xp[t][b][0..127] fp16 (cols >=100 zero)
// ---------------------------------------------------------------------------
__global__ __launch_bounds__(256) void embed_k(
    const int* __restrict__ inputs, const float* __restrict__ emb,
    char* __restrict__ ws)
{
  int r = blockIdx.x * 4 + (threadIdx.x >> 6);   // r = t*256 + b
  int lane = threadIdx.x & 63;
  int t = r >> 8, b = r & 255;
  int idx = inputs[b * SEQ + t];
  int e = lane * 2;
  f16x2 h;
  if (e < NEMB) {
    const float* src = emb + (size_t)idx * NEMB + e;
    h[0] = (f16)src[0]; h[1] = (f16)src[1];
  } else { h[0] = (f16)0.f; h[1] = (f16)0.f; }
  *(f16x2*)(ws + XP_OFF + ((size_t)r * EPAD + e) * 2) = h;
}

// ---------------------------------------------------------------------------
// one phase of GEMM work for one WG.
//  - 64-row (batch) x 64/128-col tile, K looped in BK=128 LDS tiles (dbuf)
//  - A rows staged into XOR-swizzled LDS via global_load_lds (pre-swizzled src)
//  - B frags read directly from the fragment stream (coalesced 16B/lane)
// ---------------------------------------------------------------------------
template <int RF, int CF>
__device__ __forceinline__ void phase_compute(
    const f16* __restrict__ Hr, f16* __restrict__ Hw,
    const f16* __restrict__ Bst, const f16* __restrict__ Xp,
    const float* __restrict__ bias, f16* __restrict__ Atile,
    int p, int m0, int gb, int wr_row, int out_half,
    int NBK, int NKC, bool xtail, bool force_zero)
{
  const int tid  = threadIdx.x;
  const int wave = tid >> 6, lane = tid & 63;
  const int st_r = tid >> 4;      // 0..15 (wave*4 + (lane>>4))
  const int st_q = tid & 15;

  // stage K-tile kt into LDS buffer buf (64 rows x 128 halfs, row-XOR-swizzled)
  auto stage = [&](int kt, int buf) {
    f16* base_all = Atile + buf * (64 * 128);
#pragma unroll
    for (int ro = 0; ro < 4; ++ro) {
      int r = ro * 16 + st_r;
      int kcol = (st_q ^ (r & 7)) * 8;  // pre-swizzled source chunk
      const f16* src;
      if (xtail && kt == 16)
        src = Xp + ((size_t)p * BATCH + m0 + r) * EPAD + kcol;
      else
        src = Hr + (size_t)(m0 + r) * 4096 + kt * 128 + kcol;
      f16* dst = base_all + (ro * 16 + wave * 4) * 128;   // wave-uniform base
      gl_lds16(src, dst);
    }
  };

  f32x4 acc[RF][CF];
#pragma unroll
  for (int rf = 0; rf < RF; ++rf)
#pragma unroll
    for (int cf = 0; cf < CF; ++cf)
      acc[rf][cf] = {0.f, 0.f, 0.f, 0.f};

  stage(0, 0);
  for (int kt = 0; kt < NBK; ++kt) {
    __syncthreads();                       // tile kt staged; other buf free
    if (kt + 1 < NBK) stage(kt + 1, (kt + 1) & 1);
    const f16* At = Atile + (kt & 1) * (64 * 128);
#pragma unroll
    for (int s = 0; s < 4; ++s) {          // 4 x K=32 MFMA steps per tile
      f16x8 af[RF];
#pragma unroll
      for (int rf = 0; rf < RF; ++rf) {
        int row = wr_row + rf * 16 + (lane & 15);
        int cs  = s * 4 + (lane >> 4);
        af[rf] = *(const f16x8*)(At + row * 128 + ((cs ^ (row & 7)) * 8));
      }
      int kc = kt * 4 + s;
#pragma unroll
      for (int cf = 0; cf < CF; ++cf) {
        f16x8 bf = *(const f16x8*)(Bst + ((size_t)(gb + cf) * NKC + kc) * 512 + lane * 8);
#pragma unroll
        for (int rf = 0; rf < RF; ++rf)
          acc[rf][cf] = __builtin_amdgcn_mfma_f32_16x16x32_f16(af[rf], bf, acc[rf][cf], 0, 0, 0);
      }
    }
  }

  // epilogue: bias + tanh + fp16 store. C/D layout: col=lane&15, row=(lane>>4)*4+reg
#pragma unroll
  for (int rf = 0; rf < RF; ++rf) {
#pragma unroll
    for (int cf = 0; cf < CF; ++cf) {
      int gcol = (gb + cf) * 16 + (lane & 15);
      float bv = bias[gcol];
#pragma unroll
      for (int reg = 0; reg < 4; ++reg) {
        int gr = m0 + wr_row + rf * 16 + (lane >> 4) * 4 + reg;
        float v = acc[rf][cf][reg] + bv;
        float t = force_zero ? 0.f : tanh_fast(v);
        Hw[(size_t)gr * 4096 + out_half + gcol] = (f16)t;
      }
    }
  }
}

// ---------------------------------------------------------------------------
// persistent RNN kernel: 192 WGs (64 for layer0 "Y0", 128 for layer1 "Y1")
// phase p: Y0 computes h0[p] (p<80); Y1 computes h1[p-1] (zero at p=0)
// read buf = Hbuf[(p+1)&1], write buf = Hbuf[p&1]
// ---------------------------------------------------------------------------
__global__ __launch_bounds__(256, 1) void rnn_persist(
    const float* __restrict__ b0v, const float* __restrict__ b1v,
    char* __restrict__ ws)
{
  __shared__ f16 Atile[2 * 64 * 128];            // 32 KiB, double-buffered A tile
  const int w = blockIdx.x;
  int* flags = (int*)(ws + FLAGS_OFF);
  f16* HbA = (f16*)(ws + HBUF_OFF);
  f16* HbB = (f16*)(ws + HBUF_OFF + HBUF_ONE);
  const f16* Xp = (const f16*)(ws + XP_OFF);
  const f16* B0 = (const f16*)(ws + B0S_OFF);
  const f16* B1 = (const f16*)(ws + B1S_OFF);

  const int wave = threadIdx.x >> 6;
  const bool isY0 = (w < 64);
  int m0, gb, wr_row;
  if (isY0) {                                    // 64 WGs: tile 64 x 128, K=2176
    m0 = (w >> 4) * 64;
    int n0 = (w & 15) * 128;
    wr_row = (wave >> 1) * 32;                   // 2x2 waves: 32 x 64 each
    gb = (n0 + (wave & 1) * 64) >> 4;
  } else {                                       // 128 WGs: tile 64 x 64, K=4096
    int i = w - 64;
    m0 = (i >> 5) * 64;
    int n0 = (i & 31) * 64;
    wr_row = (wave >> 1) * 32;                   // 2x2 waves: 32 x 32 each
    gb = (n0 + (wave & 1) * 32) >> 4;
  }

  for (int p = 0; p <= 80; ++p) {
    const f16* Hr = ((p + 1) & 1) ? HbB : HbA;
    f16*       Hw = (p & 1) ? HbB : HbA;
    if (isY0) {
      if (p < 80)
        phase_compute<2, 4>(Hr, Hw, B0, Xp, b0v, Atile, p, m0, gb, wr_row,
                            0, 17, B0S_NKC, true, false);
    } else {
      phase_compute<2, 2>(Hr, Hw, B1, Xp, b1v, Atile, p, m0, gb, wr_row,
                          2048, 32, B1S_NKC, false, (p == 0));
    }
    if (p < 80) gbar(flags, p + 1);
  }
}

// ---------------------------------------------------------------------------
// epilogue: logits = sigmoid(h1[79] @ Wo + bo)  -> 256 fp32
// ---------------------------------------------------------------------------
__global__ __launch_bounds__(256) void logits_k(
    const char* __restrict__ ws, const float* __restrict__ Wo,
    const float* __restrict__ bo, float* __restrict__ out)
{
  int row = blockIdx.x * 4 + (threadIdx.x >> 6);
  int lane = threadIdx.x & 63;
  const f16* h1 = (const f16*)(ws + HBUF_OFF) + (size_t)row * 4096 + 2048;
  float s = 0.f;
#pragma unroll
  for (int it = 0; it < 4; ++it) {
    int k = it * 512 + lane * 8;
    f16x8 hv = *(const f16x8*)(h1 + k);
    const float4* wp = (const float4*)(Wo + k);
    float4 w0 = wp[0], w1 = wp[1];
    s += (float)hv[0] * w0.x + (float)hv[1] * w0.y + (float)hv[2] * w0.z + (float)hv[3] * w0.w;
    s += (float)hv[4] * w1.x + (float)hv[5] * w1.y + (float)hv[6] * w1.z + (float)hv[7] * w1.w;
  }
#pragma unroll
  for (int off = 32; off > 0; off >>= 1) s += __shfl_down(s, off);
  if (lane == 0) out[row] = 1.f / (1.f + __expf(-(s + bo[0])));
}

// ---------------------------------------------------------------------------
extern "C" void kernel_launch(void* const* d_in, const int* in_sizes, int n_in,
                              void* d_out, int out_size, void* d_ws, size_t ws_size,
                              hipStream_t stream)
{
  (void)in_sizes; (void)n_in; (void)out_size;
  const int*   inputs = (const int*)d_in[0];
  const float* emb    = (const float*)d_in[1];
  const float* W0     = (const float*)d_in[2];
  const float* U0     = (const float*)d_in[3];
  const float* b0     = (const float*)d_in[4];
  const float* W1     = (const float*)d_in[5];
  const float* U1     = (const float*)d_in[6];
  const float* b1     = (const float*)d_in[7];
  const float* Wo     = (const float*)d_in[8];
  const float* bo     = (const float*)d_in[9];
  char* ws = (char*)d_ws;
  if (ws_size < WS_NEED) return;   // workspace too small -> visible validation failure

  // zero barrier flags + both h buffers (h0_init = h1_init = 0)
  hipMemsetAsync(ws, 0, HBUF_OFF + 2 * HBUF_ONE, stream);
  fmt_weights<<<6272, 256, 0, stream>>>(W0, U0, W1, U1, ws);
  embed_k<<<5120, 256, 0, stream>>>(inputs, emb, ws);
  rnn_persist<<<NWG, 256, 0, stream>>>(b0, b1, ws);
  logits_k<<<64, 256, 0, stream>>>(ws, Wo, bo, (float*)d_out);
}